// Round 1
// baseline (205.077 us; speedup 1.0000x reference)
//
#include <hip/hip_runtime.h>

#define NN 400
#define FF 240
#define CC 32
#define NIN 304   // F + 2C
#define LL 1440

// ---------------------------------------------------------------------------
// K1: P[i][c] = sb[c] + sum_f x[i][f]*sw[f*C+c]
//     Q[i][c] =         sum_f x[i][f]*sw[(F+f)*C+c]
// grid = N blocks, 64 threads: lanes 0..31 -> P, 32..63 -> Q
// ---------------------------------------------------------------------------
__global__ void pq_kernel(const float* __restrict__ x, const float* __restrict__ sw,
                          const float* __restrict__ sb,
                          float* __restrict__ P, float* __restrict__ Q) {
    const int i  = blockIdx.x;
    const int t  = threadIdx.x;
    const int cc = t & 31;
    const bool isQ = (t >= 32);
    const float* wbase = sw + (isQ ? FF * CC : 0) + cc;
    float acc = isQ ? 0.0f : sb[cc];
    const float* xrow = x + i * FF;
    #pragma unroll 4
    for (int f = 0; f < FF; ++f) {
        acc += xrow[f] * wbase[f * CC];
    }
    if (isQ) Q[i * CC + cc] = acc;
    else     P[i * CC + cc] = acc;
}

// ---------------------------------------------------------------------------
// K2/K3: per fixed index b, loop over the other index k.
//  ROW mode (COL=false): b = i, k = j; att weights = aiw; agg = agg_i; e_out opt.
//  COL mode (COL=true):  b = j, k = i; att weights = ajw; agg = agg_j.
//  s[i][j][c] = relu(P[i][c] + Q[j][c] + e[i][j]*w1[c] + e[j][i]*w2[c]) * a[i][j]
// block = 256 threads: c = t&31 (channel), g = t>>5 (j-group of 8)
// ---------------------------------------------------------------------------
template<bool COL, bool WRITE_E>
__global__ void rc_kernel(const float* __restrict__ P, const float* __restrict__ Q,
                          const float* __restrict__ e, const float* __restrict__ a,
                          const float* __restrict__ w1, const float* __restrict__ w2,
                          const float* __restrict__ attw, const float* __restrict__ attb,
                          const float* __restrict__ ew, const float* __restrict__ eb,
                          float* __restrict__ agg, float* __restrict__ e_out) {
    const int b = blockIdx.x;
    const int t = threadIdx.x;
    const int c = t & 31;
    const int g = t >> 5;   // 0..7

    const float fixed_pq = COL ? Q[b * CC + c] : P[b * CC + c];
    const float w1c = w1[c];
    const float w2c = w2[c];
    const float awc = attw[c];
    const float ewc = WRITE_E ? ew[c] : 0.0f;
    const float ab  = attb[0];
    const float ebv = WRITE_E ? eb[0] : 0.0f;

    float acc = 0.0f;
    for (int k = g; k < NN; k += 8) {
        const int i = COL ? k : b;
        const int j = COL ? b : k;
        const float var_pq = COL ? P[k * CC + c] : Q[k * CC + c];
        const float e_f = e[i * NN + j];
        const float e_r = e[j * NN + i];
        const float av  = a[i * NN + j];
        float pre = fixed_pq + var_pq + e_f * w1c + e_r * w2c;
        float s = fmaxf(pre, 0.0f) * av;
        // 32-wide dots via butterfly shuffle (groups of 32 lanes)
        float d_att = s * awc;
        float d_e   = WRITE_E ? s * ewc : 0.0f;
        #pragma unroll
        for (int m = 1; m < 32; m <<= 1) {
            d_att += __shfl_xor(d_att, m, 32);
            if (WRITE_E) d_e += __shfl_xor(d_e, m, 32);
        }
        const float att = 1.0f / (1.0f + __expf(-(d_att + ab)));
        acc += att * s;
        if (WRITE_E && c == 0) e_out[i * NN + j] = d_e + ebv;
    }

    __shared__ float red[8][CC];
    red[g][c] = acc;
    __syncthreads();
    if (t < CC) {
        float sum = 0.0f;
        #pragma unroll
        for (int gg = 0; gg < 8; ++gg) sum += red[gg][c];
        agg[b * CC + c] = sum;
    }
}

// ---------------------------------------------------------------------------
// K4: x_out[i][f] = nb[f] + sum_k concat(x[i], agg_i[i], agg_j[i])[k] * nw[k*F+f]
// grid = N blocks, 256 threads (240 active)
// ---------------------------------------------------------------------------
__global__ void node_kernel(const float* __restrict__ x, const float* __restrict__ agg_i,
                            const float* __restrict__ agg_j, const float* __restrict__ nw,
                            const float* __restrict__ nb, float* __restrict__ xout) {
    const int i = blockIdx.x;
    const int t = threadIdx.x;
    __shared__ float v[NIN];
    for (int k = t; k < NIN; k += 256) {
        float val;
        if (k < FF)           val = x[i * FF + k];
        else if (k < FF + CC) val = agg_i[i * CC + (k - FF)];
        else                  val = agg_j[i * CC + (k - FF - CC)];
        v[k] = val;
    }
    __syncthreads();
    if (t < FF) {
        float acc = nb[t];
        #pragma unroll 4
        for (int k = 0; k < NIN; ++k) acc += v[k] * nw[k * FF + t];
        xout[i * FF + t] = acc;
    }
}

// ---------------------------------------------------------------------------
// K5: out[i][l] = db[l] + sum_f x[i][f]*dw[f*L+l]
// grid = (N, 6) blocks, 256 threads
// ---------------------------------------------------------------------------
__global__ void dense_kernel(const float* __restrict__ x, const float* __restrict__ dw,
                             const float* __restrict__ db, float* __restrict__ out) {
    const int i = blockIdx.x;
    const int l = blockIdx.y * 256 + threadIdx.x;
    __shared__ float v[FF];
    for (int k = threadIdx.x; k < FF; k += 256) v[k] = x[i * FF + k];
    __syncthreads();
    if (l < LL) {
        float acc = db[l];
        #pragma unroll 4
        for (int f = 0; f < FF; ++f) acc += v[f] * dw[f * LL + l];
        out[i * LL + l] = acc;
    }
}

extern "C" void kernel_launch(void* const* d_in, const int* in_sizes, int n_in,
                              void* d_out, int out_size, void* d_ws, size_t ws_size,
                              hipStream_t stream) {
    const float* x  = (const float*)d_in[0];
    const float* a  = (const float*)d_in[1];
    const float* e0 = (const float*)d_in[2];

    const float* c1_sw  = (const float*)d_in[3];
    const float* c1_sb  = (const float*)d_in[4];
    const float* c1_aiw = (const float*)d_in[5];
    const float* c1_aib = (const float*)d_in[6];
    const float* c1_ajw = (const float*)d_in[7];
    const float* c1_ajb = (const float*)d_in[8];
    const float* c1_nw  = (const float*)d_in[9];
    const float* c1_nb  = (const float*)d_in[10];
    const float* c1_ew  = (const float*)d_in[11];
    const float* c1_eb  = (const float*)d_in[12];

    const float* c2_sw  = (const float*)d_in[13];
    const float* c2_sb  = (const float*)d_in[14];
    const float* c2_aiw = (const float*)d_in[15];
    const float* c2_aib = (const float*)d_in[16];
    const float* c2_ajw = (const float*)d_in[17];
    const float* c2_ajb = (const float*)d_in[18];
    const float* c2_nw  = (const float*)d_in[19];
    const float* c2_nb  = (const float*)d_in[20];
    const float* c2_ew  = (const float*)d_in[21];
    const float* c2_eb  = (const float*)d_in[22];

    const float* dw = (const float*)d_in[23];
    const float* db = (const float*)d_in[24];

    float* ws = (float*)d_ws;
    float* P     = ws;                 // 400*32
    float* Q     = P + NN * CC;        // 400*32
    float* agg_i = Q + NN * CC;        // 400*32
    float* agg_j = agg_i + NN * CC;    // 400*32
    float* x1    = agg_j + NN * CC;    // 400*240
    float* e1    = x1 + NN * FF;       // 400*400
    float* x2    = e1 + NN * NN;       // 400*240

    float* out = (float*)d_out;

    // ---- layer 1 ----
    pq_kernel<<<NN, 64, 0, stream>>>(x, c1_sw, c1_sb, P, Q);
    rc_kernel<false, true ><<<NN, 256, 0, stream>>>(P, Q, e0, a,
        c1_sw + 480 * CC, c1_sw + 481 * CC, c1_aiw, c1_aib, c1_ew, c1_eb, agg_i, e1);
    rc_kernel<true,  false><<<NN, 256, 0, stream>>>(P, Q, e0, a,
        c1_sw + 480 * CC, c1_sw + 481 * CC, c1_ajw, c1_ajb, c1_ew, c1_eb, agg_j, e1);
    node_kernel<<<NN, 256, 0, stream>>>(x, agg_i, agg_j, c1_nw, c1_nb, x1);

    // ---- layer 2 (e_out not needed downstream) ----
    pq_kernel<<<NN, 64, 0, stream>>>(x1, c2_sw, c2_sb, P, Q);
    rc_kernel<false, false><<<NN, 256, 0, stream>>>(P, Q, e1, a,
        c2_sw + 480 * CC, c2_sw + 481 * CC, c2_aiw, c2_aib, c2_ew, c2_eb, agg_i, (float*)nullptr);
    rc_kernel<true,  false><<<NN, 256, 0, stream>>>(P, Q, e1, a,
        c2_sw + 480 * CC, c2_sw + 481 * CC, c2_ajw, c2_ajb, c2_ew, c2_eb, agg_j, (float*)nullptr);
    node_kernel<<<NN, 256, 0, stream>>>(x1, agg_i, agg_j, c2_nw, c2_nb, x2);

    // ---- final dense ----
    dense_kernel<<<dim3(NN, 6), 256, 0, stream>>>(x2, dw, db, out);
}

// Round 2
// 107.543 us; speedup vs baseline: 1.9069x; 1.9069x over previous
//
#include <hip/hip_runtime.h>

#define NN 400
#define FF 240
#define CC 32
#define NIN 304   // F + 2C
#define LL 1440
#define KSPLIT 8
#define KCHUNK (NN / KSPLIT)   // 50

// ---------------------------------------------------------------------------
// K1: P[i][c] = sb[c] + sum_f x[i][f]*sw[f*C+c]
//     Q[i][c] =         sum_f x[i][f]*sw[(F+f)*C+c]
// grid = N blocks, 256 threads: c = t&31, isQ = (t>>5)&1, q = t>>6 (f-quarter)
// ---------------------------------------------------------------------------
__global__ void pq_kernel(const float* __restrict__ x, const float* __restrict__ sw,
                          const float* __restrict__ sb,
                          float* __restrict__ P, float* __restrict__ Q) {
    const int i   = blockIdx.x;
    const int t   = threadIdx.x;
    const int cc  = t & 31;
    const int isQ = (t >> 5) & 1;
    const int q   = t >> 6;            // 0..3, 60 f each
    const float* wbase = sw + (isQ ? FF * CC : 0) + cc;
    float acc = (!isQ && q == 0) ? sb[cc] : 0.0f;
    const float* xrow = x + i * FF;
    const int f0 = q * 60;
    #pragma unroll 4
    for (int f = f0; f < f0 + 60; ++f) {
        acc += xrow[f] * wbase[f * CC];
    }
    __shared__ float red[4][64];
    red[q][t & 63] = acc;
    __syncthreads();
    if (t < 64) {
        float s = red[0][t] + red[1][t] + red[2][t] + red[3][t];
        if (t >= 32) Q[i * CC + (t & 31)] = s;
        else         P[i * CC + t] = s;
    }
}

// ---------------------------------------------------------------------------
// K2/K3: per fixed index b and k-chunk kb, reduce over k in [kb*50, kb*50+50).
//  ROW mode (COL=false): b = i, k = j; att = aiw; partials -> agg_i; e_out opt.
//  COL mode (COL=true):  b = j, k = i; att = ajw; partials -> agg_j.
//  s[i][j][c] = relu(P[i][c] + Q[j][c] + e[i][j]*w1[c] + e[j][i]*w2[c]) * a[i][j]
// block = 256: c = t&31 (channel), g = t>>5 (k-subgroup of 8)
// partials written to agg_part[kb*N*C + b*C + c]; node_kernel sums them.
// ---------------------------------------------------------------------------
template<bool COL, bool WRITE_E>
__global__ void rc_kernel(const float* __restrict__ P, const float* __restrict__ Q,
                          const float* __restrict__ e, const float* __restrict__ a,
                          const float* __restrict__ w1, const float* __restrict__ w2,
                          const float* __restrict__ attw, const float* __restrict__ attb,
                          const float* __restrict__ ew, const float* __restrict__ eb,
                          float* __restrict__ agg_part, float* __restrict__ e_out) {
    const int b  = blockIdx.x;
    const int kb = blockIdx.y;
    const int t  = threadIdx.x;
    const int c  = t & 31;
    const int g  = t >> 5;   // 0..7

    const float fixed_pq = COL ? Q[b * CC + c] : P[b * CC + c];
    const float w1c = w1[c];
    const float w2c = w2[c];
    const float awc = attw[c];
    const float ewc = WRITE_E ? ew[c] : 0.0f;
    const float ab  = attb[0];
    const float ebv = WRITE_E ? eb[0] : 0.0f;

    float acc = 0.0f;
    const int kend = (kb + 1) * KCHUNK;
    for (int k = kb * KCHUNK + g; k < kend; k += 8) {
        const int i = COL ? k : b;
        const int j = COL ? b : k;
        const float var_pq = COL ? P[k * CC + c] : Q[k * CC + c];
        const float e_f = e[i * NN + j];
        const float e_r = e[j * NN + i];
        const float av  = a[i * NN + j];
        float pre = fixed_pq + var_pq + e_f * w1c + e_r * w2c;
        float s = fmaxf(pre, 0.0f) * av;
        float d_att = s * awc;
        float d_e   = WRITE_E ? s * ewc : 0.0f;
        #pragma unroll
        for (int m = 1; m < 32; m <<= 1) {
            d_att += __shfl_xor(d_att, m, 32);
            if (WRITE_E) d_e += __shfl_xor(d_e, m, 32);
        }
        const float att = 1.0f / (1.0f + __expf(-(d_att + ab)));
        acc += att * s;
        if (WRITE_E && c == 0) e_out[i * NN + j] = d_e + ebv;
    }

    __shared__ float red[8][CC];
    red[g][c] = acc;
    __syncthreads();
    if (t < CC) {
        float sum = 0.0f;
        #pragma unroll
        for (int gg = 0; gg < 8; ++gg) sum += red[gg][c];
        agg_part[kb * NN * CC + b * CC + c] = sum;
    }
}

// ---------------------------------------------------------------------------
// K4: x_out[i][f] = nb[f] + sum_k concat(x[i], sum_p agg_i_p[i], sum_p agg_j_p[i])[k] * nw[k*F+f]
// grid = N blocks, 512 threads: f = t&255, h = t>>8 splits the NIN dot in two.
// ---------------------------------------------------------------------------
__global__ void node_kernel(const float* __restrict__ x, const float* __restrict__ agg_i_part,
                            const float* __restrict__ agg_j_part, const float* __restrict__ nw,
                            const float* __restrict__ nb, float* __restrict__ xout) {
    const int i = blockIdx.x;
    const int t = threadIdx.x;
    const int f = t & 255;
    const int h = t >> 8;
    __shared__ float v[NIN];
    __shared__ float red[2][FF];
    if (t < NIN) {
        float val;
        if (t < FF) {
            val = x[i * FF + t];
        } else {
            const int c = t - FF;
            const float* base = (c < CC) ? (agg_i_part + i * CC + c)
                                         : (agg_j_part + i * CC + (c - CC));
            float s = 0.0f;
            #pragma unroll
            for (int p = 0; p < KSPLIT; ++p) s += base[p * NN * CC];
            val = s;
        }
        v[t] = val;
    }
    __syncthreads();
    if (f < FF) {
        float acc = (h == 0) ? nb[f] : 0.0f;
        const int k0 = h * (NIN / 2);
        #pragma unroll 4
        for (int k = k0; k < k0 + NIN / 2; ++k) acc += v[k] * nw[k * FF + f];
        red[h][f] = acc;
    }
    __syncthreads();
    if (t < FF) xout[i * FF + t] = red[0][t] + red[1][t];
}

// ---------------------------------------------------------------------------
// K5: out[i][l] = db[l] + sum_f x[i][f]*dw[f*L+l], 4 rows per block for dw reuse
// grid = (N/4, 6) blocks, 256 threads
// ---------------------------------------------------------------------------
__global__ void dense_kernel(const float* __restrict__ x, const float* __restrict__ dw,
                             const float* __restrict__ db, float* __restrict__ out) {
    const int i0 = blockIdx.x * 4;
    const int l  = blockIdx.y * 256 + threadIdx.x;
    __shared__ float xs[4][FF];
    for (int idx = threadIdx.x; idx < 4 * FF; idx += 256) {
        const int r = idx / FF;
        const int f = idx - r * FF;
        xs[r][f] = x[(i0 + r) * FF + f];
    }
    __syncthreads();
    if (l < LL) {
        float acc0 = db[l], acc1 = acc0, acc2 = acc0, acc3 = acc0;
        #pragma unroll 4
        for (int f = 0; f < FF; ++f) {
            const float dwv = dw[f * LL + l];
            acc0 += xs[0][f] * dwv;
            acc1 += xs[1][f] * dwv;
            acc2 += xs[2][f] * dwv;
            acc3 += xs[3][f] * dwv;
        }
        out[(i0 + 0) * LL + l] = acc0;
        out[(i0 + 1) * LL + l] = acc1;
        out[(i0 + 2) * LL + l] = acc2;
        out[(i0 + 3) * LL + l] = acc3;
    }
}

extern "C" void kernel_launch(void* const* d_in, const int* in_sizes, int n_in,
                              void* d_out, int out_size, void* d_ws, size_t ws_size,
                              hipStream_t stream) {
    const float* x  = (const float*)d_in[0];
    const float* a  = (const float*)d_in[1];
    const float* e0 = (const float*)d_in[2];

    const float* c1_sw  = (const float*)d_in[3];
    const float* c1_sb  = (const float*)d_in[4];
    const float* c1_aiw = (const float*)d_in[5];
    const float* c1_aib = (const float*)d_in[6];
    const float* c1_ajw = (const float*)d_in[7];
    const float* c1_ajb = (const float*)d_in[8];
    const float* c1_nw  = (const float*)d_in[9];
    const float* c1_nb  = (const float*)d_in[10];
    const float* c1_ew  = (const float*)d_in[11];
    const float* c1_eb  = (const float*)d_in[12];

    const float* c2_sw  = (const float*)d_in[13];
    const float* c2_sb  = (const float*)d_in[14];
    const float* c2_aiw = (const float*)d_in[15];
    const float* c2_aib = (const float*)d_in[16];
    const float* c2_ajw = (const float*)d_in[17];
    const float* c2_ajb = (const float*)d_in[18];
    const float* c2_nw  = (const float*)d_in[19];
    const float* c2_nb  = (const float*)d_in[20];
    const float* c2_ew  = (const float*)d_in[21];
    const float* c2_eb  = (const float*)d_in[22];

    const float* dw = (const float*)d_in[23];
    const float* db = (const float*)d_in[24];

    float* ws = (float*)d_ws;
    float* P     = ws;                         // 400*32
    float* Q     = P + NN * CC;                // 400*32
    float* aggiP = Q + NN * CC;                // 8*400*32
    float* aggjP = aggiP + KSPLIT * NN * CC;   // 8*400*32
    float* x1    = aggjP + KSPLIT * NN * CC;   // 400*240
    float* e1    = x1 + NN * FF;               // 400*400
    float* x2    = e1 + NN * NN;               // 400*240

    float* out = (float*)d_out;

    // ---- layer 1 ----
    pq_kernel<<<NN, 256, 0, stream>>>(x, c1_sw, c1_sb, P, Q);
    rc_kernel<false, true ><<<dim3(NN, KSPLIT), 256, 0, stream>>>(P, Q, e0, a,
        c1_sw + 480 * CC, c1_sw + 481 * CC, c1_aiw, c1_aib, c1_ew, c1_eb, aggiP, e1);
    rc_kernel<true,  false><<<dim3(NN, KSPLIT), 256, 0, stream>>>(P, Q, e0, a,
        c1_sw + 480 * CC, c1_sw + 481 * CC, c1_ajw, c1_ajb, c1_ew, c1_eb, aggjP, e1);
    node_kernel<<<NN, 512, 0, stream>>>(x, aggiP, aggjP, c1_nw, c1_nb, x1);

    // ---- layer 2 (e_out not needed downstream) ----
    pq_kernel<<<NN, 256, 0, stream>>>(x1, c2_sw, c2_sb, P, Q);
    rc_kernel<false, false><<<dim3(NN, KSPLIT), 256, 0, stream>>>(P, Q, e1, a,
        c2_sw + 480 * CC, c2_sw + 481 * CC, c2_aiw, c2_aib, c2_ew, c2_eb, aggiP, (float*)nullptr);
    rc_kernel<true,  false><<<dim3(NN, KSPLIT), 256, 0, stream>>>(P, Q, e1, a,
        c2_sw + 480 * CC, c2_sw + 481 * CC, c2_ajw, c2_ajb, c2_ew, c2_eb, aggjP, (float*)nullptr);
    node_kernel<<<NN, 512, 0, stream>>>(x1, aggiP, aggjP, c2_nw, c2_nb, x2);

    // ---- final dense ----
    dense_kernel<<<dim3(NN / 4, 6), 256, 0, stream>>>(x2, dw, db, out);
}

// Round 3
// 80.500 us; speedup vs baseline: 2.5475x; 1.3359x over previous
//
#include <hip/hip_runtime.h>

#define NN 400
#define FF 240
#define CC 32
#define NIN 304   // F + 2C
#define LL 1440
#define KSPLIT 8
#define KCHUNK (NN / KSPLIT)   // 50

// ---------------------------------------------------------------------------
// K1: P[i][c] = sb[c] + sum_f x[i][f]*sw[f*C+c]
//     Q[i][c] =         sum_f x[i][f]*sw[(F+f)*C+c]
// grid = N blocks, 256 threads: c = t&31, isQ = (t>>5)&1, q = t>>6 (f-quarter)
// ---------------------------------------------------------------------------
__global__ __launch_bounds__(256) void pq_kernel(
    const float* __restrict__ x, const float* __restrict__ sw,
    const float* __restrict__ sb, float* __restrict__ P, float* __restrict__ Q) {
    const int i   = blockIdx.x;
    const int t   = threadIdx.x;
    const int cc  = t & 31;
    const int isQ = (t >> 5) & 1;
    const int q   = t >> 6;            // 0..3, 60 f each
    const float* wbase = sw + (isQ ? FF * CC : 0) + cc;
    float acc = (!isQ && q == 0) ? sb[cc] : 0.0f;
    const float* xrow = x + i * FF;
    const int f0 = q * 60;
    #pragma unroll 4
    for (int f = f0; f < f0 + 60; ++f) acc += xrow[f] * wbase[f * CC];
    __shared__ float red[4][64];
    red[q][t & 63] = acc;
    __syncthreads();
    if (t < 64) {
        float s = red[0][t] + red[1][t] + red[2][t] + red[3][t];
        if (t >= 32) Q[i * CC + (t & 31)] = s;
        else         P[i * CC + t] = s;
    }
}

// ---------------------------------------------------------------------------
// K2: fused ROW+COL pair kernel. For fixed b, k-chunk kb:
//   s_row = s[b][k] -> att_i gate -> acc into agg_i[b] partial; e_out[b][k].
//   s_col = s[k][b] -> att_j gate -> acc into agg_j[b] partial.
// Mapping: 8 lanes per pair (l = t&7 holds channels c0=4l..4l+3),
//          pg = t>>3 in [0,32) pairs per iteration, 2 iterations cover 50 k.
// 3-step butterfly (masks 1,2,4) for the 32-wide gate dots.
// ---------------------------------------------------------------------------
template<bool WRITE_E>
__global__ __launch_bounds__(256) void rcf_kernel(
    const float* __restrict__ P, const float* __restrict__ Q,
    const float* __restrict__ e, const float* __restrict__ a,
    const float* __restrict__ sw_tail,   // = sw + 480*CC : rows [w1 ; w2]
    const float* __restrict__ aiw, const float* __restrict__ aib,
    const float* __restrict__ ajw, const float* __restrict__ ajb,
    const float* __restrict__ ew, const float* __restrict__ eb,
    float* __restrict__ aggi_part, float* __restrict__ aggj_part,
    float* __restrict__ e_out) {
    const int b  = blockIdx.x;
    const int kb = blockIdx.y;
    const int t  = threadIdx.x;
    const int pg = t >> 3;   // pair-group 0..31
    const int l  = t & 7;    // sub-lane
    const int c0 = l * 4;

    float w1v[4], w2v[4], wiv[4], wjv[4], wev[4], Pb[4], Qb[4];
    *(float4*)w1v = *(const float4*)(sw_tail + c0);
    *(float4*)w2v = *(const float4*)(sw_tail + CC + c0);
    *(float4*)wiv = *(const float4*)(aiw + c0);
    *(float4*)wjv = *(const float4*)(ajw + c0);
    if (WRITE_E) *(float4*)wev = *(const float4*)(ew + c0);
    *(float4*)Pb  = *(const float4*)(P + b * CC + c0);
    *(float4*)Qb  = *(const float4*)(Q + b * CC + c0);
    const float bi = aib[0], bj = ajb[0];
    const float be = WRITE_E ? eb[0] : 0.0f;

    float acc_i[4] = {0, 0, 0, 0};
    float acc_j[4] = {0, 0, 0, 0};
    const int kbase = kb * KCHUNK;

    #pragma unroll
    for (int it = 0; it < 2; ++it) {
        const int off = it * 32 + pg;
        const bool valid = off < KCHUNK;
        const int k = kbase + (valid ? off : 0);
        float Qk[4], Pk[4];
        *(float4*)Qk = *(const float4*)(Q + k * CC + c0);
        *(float4*)Pk = *(const float4*)(P + k * CC + c0);
        const float e_f  = e[b * NN + k];
        const float e_r  = e[k * NN + b];
        const float a_bk = a[b * NN + k];
        const float a_kb = a[k * NN + b];

        float sr[4], sc[4];
        #pragma unroll
        for (int q = 0; q < 4; ++q) {
            sr[q] = fmaxf(Pb[q] + Qk[q] + e_f * w1v[q] + e_r * w2v[q], 0.0f) * a_bk;
            sc[q] = fmaxf(Pk[q] + Qb[q] + e_r * w1v[q] + e_f * w2v[q], 0.0f) * a_kb;
        }
        float d_i = sr[0] * wiv[0] + sr[1] * wiv[1] + sr[2] * wiv[2] + sr[3] * wiv[3];
        float d_j = sc[0] * wjv[0] + sc[1] * wjv[1] + sc[2] * wjv[2] + sc[3] * wjv[3];
        float d_e = WRITE_E ? (sr[0] * wev[0] + sr[1] * wev[1] + sr[2] * wev[2] + sr[3] * wev[3]) : 0.0f;
        #pragma unroll
        for (int m = 1; m < 8; m <<= 1) {
            d_i += __shfl_xor(d_i, m);
            d_j += __shfl_xor(d_j, m);
            if (WRITE_E) d_e += __shfl_xor(d_e, m);
        }
        const float gi = valid ? 1.0f / (1.0f + __expf(-(d_i + bi))) : 0.0f;
        const float gj = valid ? 1.0f / (1.0f + __expf(-(d_j + bj))) : 0.0f;
        #pragma unroll
        for (int q = 0; q < 4; ++q) {
            acc_i[q] += gi * sr[q];
            acc_j[q] += gj * sc[q];
        }
        if (WRITE_E && l == 0 && valid) e_out[b * NN + k] = d_e + be;
    }

    __shared__ float red[2][32][36];
    #pragma unroll
    for (int q = 0; q < 4; ++q) {
        red[0][pg][c0 + q] = acc_i[q];
        red[1][pg][c0 + q] = acc_j[q];
    }
    __syncthreads();
    if (t < 64) {
        const int which = t >> 5;
        const int c = t & 31;
        float s = 0.0f;
        #pragma unroll
        for (int g2 = 0; g2 < 32; ++g2) s += red[which][g2][c];
        float* dst = which ? aggj_part : aggi_part;
        dst[kb * NN * CC + b * CC + c] = s;
    }
}

// ---------------------------------------------------------------------------
// K3: node model fused with next layer's P/Q projection.
//   x_out[i] = nb + concat(x[i], sum_p aggi_p[i], sum_p aggj_p[i]) @ nw
//   if DO_PQ: P[i] = sb + x_out[i] @ sw[0:F]; Q[i] = x_out[i] @ sw[F:2F]
// grid = N blocks, 512 threads.
// ---------------------------------------------------------------------------
template<bool DO_PQ>
__global__ __launch_bounds__(512) void nodepq_kernel(
    const float* __restrict__ x, const float* __restrict__ aggi_part,
    const float* __restrict__ aggj_part, const float* __restrict__ nw,
    const float* __restrict__ nb,
    const float* __restrict__ sw, const float* __restrict__ sb,
    float* __restrict__ xout, float* __restrict__ Pout, float* __restrict__ Qout) {
    const int i = blockIdx.x;
    const int t = threadIdx.x;
    __shared__ float v[NIN];
    __shared__ float red[2][FF];
    __shared__ float xs[FF];
    if (t < NIN) {
        float val;
        if (t < FF) {
            val = x[i * FF + t];
        } else {
            const int c = t - FF;
            const float* base = (c < CC) ? (aggi_part + i * CC + c)
                                         : (aggj_part + i * CC + (c - CC));
            float s = 0.0f;
            #pragma unroll
            for (int p = 0; p < KSPLIT; ++p) s += base[p * NN * CC];
            val = s;
        }
        v[t] = val;
    }
    __syncthreads();
    const int f = t & 255;
    const int h = t >> 8;
    if (f < FF) {
        float acc = (h == 0) ? nb[f] : 0.0f;
        const int k0 = h * (NIN / 2);
        #pragma unroll 4
        for (int k = k0; k < k0 + NIN / 2; ++k) acc += v[k] * nw[k * FF + f];
        red[h][f] = acc;
    }
    __syncthreads();
    if (t < FF) {
        const float r = red[0][t] + red[1][t];
        xout[i * FF + t] = r;
        xs[t] = r;
    }
    if (DO_PQ) {
        __syncthreads();
        const int c   = t & 31;
        const int isQ = (t >> 5) & 1;
        const int g   = t >> 6;   // 0..7, 30 f each
        const float* wb = sw + (isQ ? FF * CC : 0) + c;
        float acc = (!isQ && g == 0) ? sb[c] : 0.0f;
        const int f0 = g * 30;
        #pragma unroll 5
        for (int f2 = f0; f2 < f0 + 30; ++f2) acc += xs[f2] * wb[f2 * CC];
        __shared__ float red2[8][64];
        red2[g][t & 63] = acc;
        __syncthreads();
        if (t < 64) {
            float s = 0.0f;
            #pragma unroll
            for (int g2 = 0; g2 < 8; ++g2) s += red2[g2][t];
            if (t >= 32) Qout[i * CC + (t & 31)] = s;
            else         Pout[i * CC + t] = s;
        }
    }
}

// ---------------------------------------------------------------------------
// K4: out[i][l] = db[l] + sum_f x[i][f]*dw[f*L+l], 4 rows per block for dw reuse
// grid = (N/4, 6) blocks, 256 threads
// ---------------------------------------------------------------------------
__global__ __launch_bounds__(256) void dense_kernel(
    const float* __restrict__ x, const float* __restrict__ dw,
    const float* __restrict__ db, float* __restrict__ out) {
    const int i0 = blockIdx.x * 4;
    const int l  = blockIdx.y * 256 + threadIdx.x;
    __shared__ float xs[4][FF];
    for (int idx = threadIdx.x; idx < 4 * FF; idx += 256) {
        const int r = idx / FF;
        const int f = idx - r * FF;
        xs[r][f] = x[(i0 + r) * FF + f];
    }
    __syncthreads();
    if (l < LL) {
        float acc0 = db[l], acc1 = acc0, acc2 = acc0, acc3 = acc0;
        #pragma unroll 4
        for (int f = 0; f < FF; ++f) {
            const float dwv = dw[f * LL + l];
            acc0 += xs[0][f] * dwv;
            acc1 += xs[1][f] * dwv;
            acc2 += xs[2][f] * dwv;
            acc3 += xs[3][f] * dwv;
        }
        out[(i0 + 0) * LL + l] = acc0;
        out[(i0 + 1) * LL + l] = acc1;
        out[(i0 + 2) * LL + l] = acc2;
        out[(i0 + 3) * LL + l] = acc3;
    }
}

extern "C" void kernel_launch(void* const* d_in, const int* in_sizes, int n_in,
                              void* d_out, int out_size, void* d_ws, size_t ws_size,
                              hipStream_t stream) {
    const float* x  = (const float*)d_in[0];
    const float* a  = (const float*)d_in[1];
    const float* e0 = (const float*)d_in[2];

    const float* c1_sw  = (const float*)d_in[3];
    const float* c1_sb  = (const float*)d_in[4];
    const float* c1_aiw = (const float*)d_in[5];
    const float* c1_aib = (const float*)d_in[6];
    const float* c1_ajw = (const float*)d_in[7];
    const float* c1_ajb = (const float*)d_in[8];
    const float* c1_nw  = (const float*)d_in[9];
    const float* c1_nb  = (const float*)d_in[10];
    const float* c1_ew  = (const float*)d_in[11];
    const float* c1_eb  = (const float*)d_in[12];

    const float* c2_sw  = (const float*)d_in[13];
    const float* c2_sb  = (const float*)d_in[14];
    const float* c2_aiw = (const float*)d_in[15];
    const float* c2_aib = (const float*)d_in[16];
    const float* c2_ajw = (const float*)d_in[17];
    const float* c2_ajb = (const float*)d_in[18];
    const float* c2_nw  = (const float*)d_in[19];
    const float* c2_nb  = (const float*)d_in[20];
    const float* c2_ew  = (const float*)d_in[21];
    const float* c2_eb  = (const float*)d_in[22];

    const float* dw = (const float*)d_in[23];
    const float* db = (const float*)d_in[24];

    float* ws = (float*)d_ws;
    float* P     = ws;                         // 400*32
    float* Q     = P + NN * CC;                // 400*32
    float* aggiP = Q + NN * CC;                // 8*400*32
    float* aggjP = aggiP + KSPLIT * NN * CC;   // 8*400*32
    float* x1    = aggjP + KSPLIT * NN * CC;   // 400*240
    float* e1    = x1 + NN * FF;               // 400*400
    float* x2    = e1 + NN * NN;               // 400*240

    float* out = (float*)d_out;

    // ---- layer 1 ----
    pq_kernel<<<NN, 256, 0, stream>>>(x, c1_sw, c1_sb, P, Q);
    rcf_kernel<true><<<dim3(NN, KSPLIT), 256, 0, stream>>>(P, Q, e0, a,
        c1_sw + 480 * CC, c1_aiw, c1_aib, c1_ajw, c1_ajb, c1_ew, c1_eb,
        aggiP, aggjP, e1);
    nodepq_kernel<true><<<NN, 512, 0, stream>>>(x, aggiP, aggjP, c1_nw, c1_nb,
        c2_sw, c2_sb, x1, P, Q);

    // ---- layer 2 (e_out not needed downstream) ----
    rcf_kernel<false><<<dim3(NN, KSPLIT), 256, 0, stream>>>(P, Q, e1, a,
        c2_sw + 480 * CC, c2_aiw, c2_aib, c2_ajw, c2_ajb, c2_ew, c2_eb,
        aggiP, aggjP, (float*)nullptr);
    nodepq_kernel<false><<<NN, 512, 0, stream>>>(x1, aggiP, aggjP, c2_nw, c2_nb,
        (const float*)nullptr, (const float*)nullptr, x2, (float*)nullptr, (float*)nullptr);

    // ---- final dense ----
    dense_kernel<<<dim3(NN / 4, 6), 256, 0, stream>>>(x2, dw, db, out);
}